// Round 8
// baseline (207.530 us; speedup 1.0000x reference)
//
#include <hip/hip_runtime.h>

// Problem constants (b=2, c=64, h=w=96)
#define NPOS 9216
#define NB 2
#define CCH 64
#define JSPLIT 2
#define JCHUNK (NPOS / JSPLIT)   // 4608
#define NSTEP (JCHUNK / 64)      // 72
#define PART_STRIDE ((size_t)NB * CCH * NPOS)   // floats per j-half partial

typedef __attribute__((ext_vector_type(8))) short short8;
typedef __attribute__((ext_vector_type(4))) short short4b;
typedef __attribute__((ext_vector_type(4))) float f32x4;
typedef __attribute__((ext_vector_type(16))) float f32x16;

#define LOG2E 1.4426950408889634f

// K=16 bf16 MFMA (v_mfma_f32_16x16x16_bf16; clang name is the gfx90a-era _1k).
__device__ __forceinline__ f32x4 mfma16(short4b a, short4b b, f32x4 c) {
#if defined(__HIP_DEVICE_COMPILE__)
    return __builtin_amdgcn_mfma_f32_16x16x16bf16_1k(a, b, c, 0, 0, 0);
#else
    return c;
#endif
}

// f32 -> bf16 bits, round-to-nearest-even (cold paths)
__device__ __forceinline__ ushort f2bf(float x) {
    unsigned u = __builtin_bit_cast(unsigned, x);
    u += 0x7FFFu + ((u >> 16) & 1u);
    return (ushort)(u >> 16);
}

__device__ __forceinline__ unsigned cvt_pk_bf16(float lo, float hi) {
    unsigned r;
    asm("v_cvt_pk_bf16_f32 %0, %1, %2" : "=v"(r) : "v"(lo), "v"(hi));
    return r;
}

// ---------------------------------------------------------------------------
// K1: 1x1 convs. q (pre-scaled by log2e),k -> bf16 [b][n][8];
// vT -> bf16 [b][c][n] unscaled. float4 weight reads (no scalar LDS storm).
// Block = 256 thr = 32 positions x 8 slices (8 ch each); 576 blocks.
// ---------------------------------------------------------------------------
__global__ __launch_bounds__(256) void qkv_kernel(
    const float* __restrict__ X, const float* __restrict__ Y,
    const float* __restrict__ Wq, const float* __restrict__ bq,
    const float* __restrict__ Wk, const float* __restrict__ bk,
    const float* __restrict__ Wv, const float* __restrict__ bv,
    ushort* __restrict__ qb, ushort* __restrict__ kb,
    ushort* __restrict__ vT)
{
    __shared__ float wqkT[1024];   // [c][16]: o<8 Wq, o>=8 Wk
    __shared__ float wvTs[4096];   // [c][64]
    int tid = threadIdx.x;
    for (int idx = tid; idx < 1024; idx += 256) {
        int c = idx >> 4, o = idx & 15;
        wqkT[idx] = (o < 8) ? Wq[o * 64 + c] : Wk[(o - 8) * 64 + c];
    }
    for (int idx = tid; idx < 4096; idx += 256) {
        int c = idx >> 6, o = idx & 63;
        wvTs[idx] = Wv[o * 64 + c];
    }
    __syncthreads();

    int p = tid & 31, s = tid >> 5;       // s: 8-channel slice
    int base = blockIdx.x * 32;
    int b = base / NPOS;
    int n = (base % NPOS) + p;

    float va[8], qk[8];
    #pragma unroll
    for (int o = 0; o < 8; ++o) va[o] = bv[s * 8 + o];
    #pragma unroll
    for (int o = 0; o < 8; ++o) qk[o] = 0.f;
    if (s == 0) {
        #pragma unroll
        for (int o = 0; o < 8; ++o) qk[o] = bq[o];
    } else if (s == 1) {
        #pragma unroll
        for (int o = 0; o < 8; ++o) qk[o] = bk[o];
    }

    const float* Xb = X + (size_t)b * CCH * NPOS + n;
    const float* Yb = Y + (size_t)b * CCH * NPOS + n;
    for (int c = 0; c < 64; ++c) {
        float yv = Yb[(size_t)c * NPOS];
        const float4* wv4 = (const float4*)(wvTs + c * 64 + s * 8);
        float4 w0 = wv4[0], w1 = wv4[1];
        va[0] += w0.x * yv; va[1] += w0.y * yv;
        va[2] += w0.z * yv; va[3] += w0.w * yv;
        va[4] += w1.x * yv; va[5] += w1.y * yv;
        va[6] += w1.z * yv; va[7] += w1.w * yv;
        if (s < 2) {
            float xv = Xb[(size_t)c * NPOS];
            const float4* wq4 = (const float4*)(wqkT + c * 16 + s * 8);
            float4 q0 = wq4[0], q1 = wq4[1];
            qk[0] += q0.x * xv; qk[1] += q0.y * xv;
            qk[2] += q0.z * xv; qk[3] += q0.w * xv;
            qk[4] += q1.x * xv; qk[5] += q1.y * xv;
            qk[6] += q1.z * xv; qk[7] += q1.w * xv;
        }
    }

    ushort* vdst = vT + (size_t)b * CCH * NPOS + n;
    #pragma unroll
    for (int o = 0; o < 8; ++o)
        vdst[(size_t)(s * 8 + o) * NPOS] = f2bf(va[o]);
    if (s < 2) {
        if (s == 0) {   // fold log2e into q so both passes use raw exp2
            #pragma unroll
            for (int o = 0; o < 8; ++o) qk[o] *= LOG2E;
        }
        short8 row;
        #pragma unroll
        for (int o = 0; o < 8; ++o) row[o] = (short)f2bf(qk[o]);
        ushort* dst = (s == 0 ? qb : kb) + ((size_t)b * NPOS + n) * 8;
        *(short8*)dst = row;
    }
}

// ---------------------------------------------------------------------------
// K2: Z[b][j] = sum_i exp2(q_i . k_j) via 32x32x16 MFMA (K pad 8->16).
// grid (72 j128-blocks, 8 i-splits, b); atomicAdd partials (only 73K atomics).
// ---------------------------------------------------------------------------
__global__ __launch_bounds__(256) void zpass_kernel(
    const ushort* __restrict__ qb, const ushort* __restrict__ kb,
    float* __restrict__ Z)
{
    int tid = threadIdx.x;
    int w = tid >> 6, l = tid & 63;
    int il2 = l & 31, h = l >> 5;
    int b = blockIdx.z;
    int jb = blockIdx.x * 128 + w * 32;
    int i0 = blockIdx.y * 1152;
    const short8 zero8 = {0,0,0,0,0,0,0,0};
    f32x16 cz16;
    #pragma unroll
    for (int r = 0; r < 16; ++r) cz16[r] = 0.f;

    short8 kf = zero8;
    if (h == 0) kf = *(const short8*)(kb + ((size_t)b * NPOS + jb + il2) * 8);

    f32x16 za = cz16;
    const ushort* qrow = qb + ((size_t)b * NPOS + i0 + il2) * 8;
    short8 qf = (h == 0) ? *(const short8*)qrow : zero8;
    for (int it = 0; it < 36; ++it) {
        short8 qn = zero8;
        if (h == 0 && (it + 1) < 36)
            qn = *(const short8*)(qrow + (size_t)(it + 1) * 256);
        f32x16 sv = __builtin_amdgcn_mfma_f32_32x32x16_bf16(kf, qf, cz16, 0, 0, 0);
        #pragma unroll
        for (int r = 0; r < 16; ++r) za[r] += __builtin_amdgcn_exp2f(sv[r]);
        qf = qn;
    }
    #pragma unroll
    for (int r = 0; r < 16; ++r) {
        float x = za[r];
        x += __shfl_xor(x, 1, 32);
        x += __shfl_xor(x, 2, 32);
        x += __shfl_xor(x, 4, 32);
        x += __shfl_xor(x, 8, 32);
        x += __shfl_xor(x, 16, 32);
        za[r] = x;
    }
    if (il2 == 0) {
        #pragma unroll
        for (int r = 0; r < 16; ++r) {
            int j = jb + (r & 3) + 8 * (r >> 2) + 4 * h;
            atomicAdd(&Z[(size_t)b * NPOS + j], za[r]);
        }
    }
}

// ---------------------------------------------------------------------------
// K3: part[jh][b][c][i] = sum_{j in half} (exp2(q_i.k_j)/Z[j]) * vT[c][j].
// 4 waves split j (16 each); PV B-frag == S-output regs (K=16 MFMA).
// Staging: lane slot = l&7 (conflict-free writes), logical chunk via XOR
// inverse; reads use slot = rslot^(row&7) (2-way free). NO atomics:
// pitch-20 LDS transpose-reduce then coalesced float4 streaming stores.
// grid (144 i-blocks of 64, JSPLIT, b).
// ---------------------------------------------------------------------------
__global__ __launch_bounds__(256) void pass2_kernel(
    const ushort* __restrict__ qb, const ushort* __restrict__ kb,
    const ushort* __restrict__ vT, const float* __restrict__ Z,
    float* __restrict__ part)
{
    __shared__ ushort vz[2][64 * 64];   // 16 KB; rows c, 8 slots of 8 j
    __shared__ float red[4 * 1280];     // 20 KB; pitch-20 reduce buffer
    int tid = threadIdx.x;
    int w = tid >> 6, l = tid & 63;
    int il = l & 15, g = l >> 4;
    int b = blockIdx.z;
    int jh = blockIdx.y;
    int ibase = blockIdx.x * 64;
    int j0 = jh * JCHUNK;
    int jw = w * 16;                    // wave's j offset inside the 64-j step

    const short8 zero8 = {0,0,0,0,0,0,0,0};
    const f32x4 cz = {0.f,0.f,0.f,0.f};

    short8 qf[4];
    #pragma unroll
    for (int it = 0; it < 4; ++it) {
        qf[it] = zero8;
        if (g == 0)
            qf[it] = *(const short8*)(qb + ((size_t)b * NPOS + ibase + it * 16 + il) * 8);
    }

    f32x4 acc[4][4];
    #pragma unroll
    for (int cg = 0; cg < 4; ++cg)
        #pragma unroll
        for (int it = 0; it < 4; ++it) acc[cg][it] = cz;

    const ushort* kbb = kb + (size_t)b * NPOS * 8;
    const float* Zb = Z + (size_t)b * NPOS;

    // staging map: lane l stages rows r0 and r0+8 at stored slot l&7.
    int r0 = w * 16 + (l >> 3);
    int sl = l & 7;
    int jq = sl ^ (r0 & 7);             // logical 8-j chunk this slot holds
    const ushort* vsrc0 = vT + (size_t)b * CCH * NPOS + (size_t)r0 * NPOS + j0 + jq * 8;
    const ushort* vsrc1 = vsrc0 + (size_t)8 * NPOS;
    int wo0 = r0 * 64 + sl * 8;
    int wo1 = wo0 + 8 * 64;

    // prologue: stage tile 0, prefetch step-0 K and Z
    {
        float4 ga = *(const float4*)vsrc0;
        float4 gb = *(const float4*)vsrc1;
        *(float4*)&vz[0][wo0] = ga;
        *(float4*)&vz[0][wo1] = gb;
    }
    short8 kf = zero8;
    if (g == 0) kf = *(const short8*)(kbb + (size_t)(j0 + jw + il) * 8);
    float4 Zv = *(const float4*)(Zb + j0 + jw + 4 * g);
    __syncthreads();

    int rslot = 2 * w + (g >> 1);   // wave's 16B slot on the read side
    int rbyte = (g & 1) * 4;        // ushort offset within slot

    for (int st = 0; st < NSTEP; ++st) {
        int cur = st & 1;
        bool more = (st + 1) < NSTEP;

        float4 ga = {0,0,0,0}, gb = {0,0,0,0}, Zn = {0,0,0,0};
        short8 kn = zero8;
        if (more) {
            int jn = (st + 1) * 64;
            ga = *(const float4*)(vsrc0 + jn);
            gb = *(const float4*)(vsrc1 + jn);
            if (g == 0) kn = *(const short8*)(kbb + (size_t)(j0 + jn + jw + il) * 8);
            Zn = *(const float4*)(Zb + j0 + jn + jw + 4 * g);
        }

        // S^T: D[j=4g+r][i=il] per i-tile (K pad 8->32)
        f32x4 sv[4];
        #pragma unroll
        for (int it = 0; it < 4; ++it)
            sv[it] = __builtin_amdgcn_mfma_f32_16x16x32_bf16(kf, qf[it], cz, 0, 0, 0);

        float rz0 = __builtin_amdgcn_rcpf(Zv.x);
        float rz1 = __builtin_amdgcn_rcpf(Zv.y);
        float rz2 = __builtin_amdgcn_rcpf(Zv.z);
        float rz3 = __builtin_amdgcn_rcpf(Zv.w);

        // P = exp2(s)/Z -> bf16 pairs; regs ARE the PV B-frags (k=4g+e)
        short4b pf[4];
        #pragma unroll
        for (int it = 0; it < 4; ++it) {
            float p0 = __builtin_amdgcn_exp2f(sv[it][0]) * rz0;
            float p1 = __builtin_amdgcn_exp2f(sv[it][1]) * rz1;
            float p2 = __builtin_amdgcn_exp2f(sv[it][2]) * rz2;
            float p3 = __builtin_amdgcn_exp2f(sv[it][3]) * rz3;
            uint2 u;
            u.x = cvt_pk_bf16(p0, p1);
            u.y = cvt_pk_bf16(p2, p3);
            pf[it] = __builtin_bit_cast(short4b, u);
        }

        // PV: acc[c16][i16] += vz[c][wave's 16 j] x P^T  (K=16 MFMA)
        #pragma unroll
        for (int cg = 0; cg < 4; ++cg) {
            int row = cg * 16 + il;
            short4b af = *(short4b*)&vz[cur][row * 64 + ((rslot ^ (row & 7)) * 8) + rbyte];
            #pragma unroll
            for (int it = 0; it < 4; ++it)
                acc[cg][it] = mfma16(af, pf[it], acc[cg][it]);
        }

        if (more) {
            *(float4*)&vz[cur ^ 1][wo0] = ga;
            *(float4*)&vz[cur ^ 1][wo1] = gb;
            kf = kn; Zv = Zn;
        }
        __syncthreads();
    }

    // epilogue: cross-wave reduce ([i][c] pitch-20), coalesced [c][n] stores
    float* pbase = part + (size_t)jh * PART_STRIDE + (size_t)b * CCH * NPOS + ibase;
    int c_l = tid >> 4, i0 = (tid & 15) * 4;
    #pragma unroll
    for (int cg = 0; cg < 4; ++cg) {
        #pragma unroll
        for (int it = 0; it < 4; ++it)
            *(f32x4*)&red[w * 1280 + (it * 16 + il) * 20 + 4 * g] = acc[cg][it];
        __syncthreads();
        float4 sum;
        float* sp = (float*)&sum;
        #pragma unroll
        for (int d = 0; d < 4; ++d) {
            int o = (i0 + d) * 20 + c_l;
            sp[d] = red[o] + red[1280 + o] + red[2560 + o] + red[3840 + o];
        }
        *(float4*)&pbase[(size_t)(cg * 16 + c_l) * NPOS + i0] = sum;
        __syncthreads();
    }
}

// ---------------------------------------------------------------------------
// K4: out = Y + part0 + part1 (pure streaming float4)
// ---------------------------------------------------------------------------
__global__ __launch_bounds__(256) void combine_kernel(
    const float* __restrict__ Y, const float* __restrict__ part,
    float* __restrict__ out)
{
    size_t idx = ((size_t)blockIdx.x * 256 + threadIdx.x) * 4;
    float4 y = *(const float4*)(Y + idx);
    float4 a = *(const float4*)(part + idx);
    float4 c = *(const float4*)(part + PART_STRIDE + idx);
    float4 o;
    o.x = y.x + a.x + c.x;
    o.y = y.y + a.y + c.y;
    o.z = y.z + a.z + c.z;
    o.w = y.w + a.w + c.w;
    *(float4*)(out + idx) = o;
}

extern "C" void kernel_launch(void* const* d_in, const int* in_sizes, int n_in,
                              void* d_out, int out_size, void* d_ws, size_t ws_size,
                              hipStream_t stream) {
    const float* X  = (const float*)d_in[0];
    const float* Y  = (const float*)d_in[1];
    const float* Wq = (const float*)d_in[2];
    const float* bq = (const float*)d_in[3];
    const float* Wk = (const float*)d_in[4];
    const float* bk = (const float*)d_in[5];
    const float* Wv = (const float*)d_in[6];
    const float* bv = (const float*)d_in[7];

    char* ws = (char*)d_ws;
    ushort* qb   = (ushort*)(ws);             // 2*9216*8 bf16   = 294912 B
    ushort* kbw  = (ushort*)(ws + 294912);    // 294912 B
    ushort* vT   = (ushort*)(ws + 589824);    // 2*64*9216 bf16  = 2359296 B
    float*  Z    = (float*) (ws + 2949120);   // 18432 f32       = 73728 B
    float*  part = (float*) (ws + 3022848);   // 2*1179648 f32   = 9437184 B
    // total ws use ~12.5 MB

    (void)hipMemsetAsync(Z, 0, (size_t)NB * NPOS * sizeof(float), stream);

    qkv_kernel<<<576, 256, 0, stream>>>(X, Y, Wq, bq, Wk, bk, Wv, bv,
                                        qb, kbw, vT);
    zpass_kernel<<<dim3(72, 8, NB), 256, 0, stream>>>(qb, kbw, Z);
    pass2_kernel<<<dim3(144, JSPLIT, NB), 256, 0, stream>>>(qb, kbw, vT, Z, part);
    combine_kernel<<<1152, 256, 0, stream>>>(Y, part, (float*)d_out);
}